// Round 9
// baseline (321.725 us; speedup 1.0000x reference)
//
#include <hip/hip_runtime.h>

// AI4Urban fused CFD timestep on 128^3 f32 grid.
// Round 9: LDS plane-march v2 — staging index math hoisted into a packed
// per-thread table (computed once; the r8 kernel recomputed non-pow2 integer
// divisions 16x per plane = the 29us VALU sink), 3-slot ring (47.5KB),
// ZSEG=2 with 1024 blocks for residency. Everything else = r7 best.

#define NN 128
#define NF (NN*NN*NN)   // 2097152

#define YB 8
#define ZSEG 2
#define SLABW 132                    // padded row
#define SROWS 10                     // YB + 2
#define SFLD (SROWS*SLABW)           // 1320
#define SLAB3 (3*SFLD)               // 3960 floats per plane (3 fields)
#define NIT 16                       // ceil(3960/256)

// ---------- packed staging table ----------

// pk_aux bits: [0:11] ds offset (0..3959), [12:13] field, [14] rn, [15] valid
__device__ __forceinline__ void stage_precompute(int tid, int y0,
                                                 int pk_src[NIT], int pk_aux[NIT]) {
#pragma unroll
  for (int it = 0; it < NIT; ++it) {
    int j = tid + it*256;
    bool val = (j < SLAB3);
    int jj = val ? j : 0;
    int f = jj / SFLD;
    int rem = jj - f*SFLD;
    int ry = rem / SLABW;
    int rx = rem - ry*SLABW;
    val = val && (rx < 130);
    int ly = y0 - 1 + ry, lx = rx - 1;
    int gy = min(max(ly, 0), NN-1), gx = min(max(lx, 0), NN-1);
    bool rn = (ly < 0) | (ly > NN-1) | (lx < 0) | (lx > NN-1);
    pk_src[it] = (gy << 7) + gx;
    pk_aux[it] = jj | (f << 12) | (rn ? 1<<14 : 0) | (val ? 1<<15 : 0);
  }
}

// Stage plane zp (logical, [-1..128]) of {su,sv,sw}; field 0 gets -1 on halo.
__device__ __forceinline__ void stage_plane2(
    float* __restrict__ slab, int slot, int zp,
    const float* __restrict__ su, const float* __restrict__ sv,
    const float* __restrict__ sw,
    const int pk_src[NIT], const int pk_aux[NIT]) {
  int gz = zp < 0 ? 0 : (zp > NN-1 ? NN-1 : zp);
  bool zoob = (zp < 0) | (zp > NN-1);
  int zbase = gz << 14;
  float* sb = slab + (size_t)slot * SLAB3;
#pragma unroll
  for (int it = 0; it < NIT; ++it) {
    int a = pk_aux[it];
    if (a & (1<<15)) {
      int f = (a >> 12) & 3;
      const float* p = (f == 0) ? su : ((f == 1) ? sv : sw);
      float v = p[zbase + pk_src[it]];
      if (f == 0 && ((a & (1<<14)) || zoob)) v = -v;
      sb[a & 0xFFF] = v;
    }
  }
}

// ---------- generic helpers (r7) ----------

__device__ __forceinline__ void prep9(int z, int y, int rb[9], bool rn[9]) {
  int zi[3] = {z > 0 ? z-1 : 0, z, z < NN-1 ? z+1 : NN-1};
  int yi[3] = {y > 0 ? y-1 : 0, y, y < NN-1 ? y+1 : NN-1};
  bool zo[3] = {z == 0, false, z == NN-1};
  bool yo[3] = {y == 0, false, y == NN-1};
#pragma unroll
  for (int a = 0; a < 3; ++a)
#pragma unroll
    for (int b = 0; b < 3; ++b) {
      rb[a*3+b] = (zi[a]*NN + yi[b])*NN;
      rn[a*3+b] = zo[a] | yo[b];
    }
}

template<bool NEG>
__device__ __forceinline__ void sten4(
    const float* __restrict__ f, const int rb[9], const bool rn[9],
    bool lo, bool hi, int x0,
    const float* __restrict__ w0p, const float* __restrict__ w1p,
    const float* __restrict__ w2p, const float* __restrict__ w3p,
    float acc[4][4], float4* center) {
  const float* const Ws[4] = {w0p, w1p, w2p, w3p};
#pragma unroll
  for (int r = 0; r < 9; ++r) {
    int base = rb[r] + x0;
    float4 c = *(const float4*)(f + base);
    float m1 = f[base - (lo ? 0 : 1)];
    float p4 = f[base + (hi ? 3 : 4)];
    if (NEG) {
      float sr = rn[r] ? -1.f : 1.f;
      m1 *= (rn[r] | lo) ? -1.f : 1.f;
      p4 *= (rn[r] | hi) ? -1.f : 1.f;
      c.x *= sr; c.y *= sr; c.z *= sr; c.w *= sr;
    }
    if (r == 4 && center) *center = c;
    float t[6] = {m1, c.x, c.y, c.z, c.w, p4};
#pragma unroll
    for (int s = 0; s < 4; ++s) {
      const float* W = Ws[s];
      float a0 = W[r*3+0], a1 = W[r*3+1], a2 = W[r*3+2];
#pragma unroll
      for (int k = 0; k < 4; ++k)
        acc[s][k] = fmaf(a0, t[k], fmaf(a1, t[k+1], fmaf(a2, t[k+2], acc[s][k])));
    }
  }
}

__device__ __forceinline__ void sten_p3(
    const float* __restrict__ f, const int rb[9],
    bool lo, bool hi, int x0,
    const float* __restrict__ w0p, const float* __restrict__ w1p,
    const float* __restrict__ w2p, float acc[3][4]) {
  const float* const Ws[3] = {w0p, w1p, w2p};
#pragma unroll
  for (int r = 0; r < 9; ++r) {
    int base = rb[r] + x0;
    float4 c = *(const float4*)(f + base);
    float m1 = f[base - (lo ? 0 : 1)];
    float p4 = f[base + (hi ? 3 : 4)];
    float t[6] = {m1, c.x, c.y, c.z, c.w, p4};
#pragma unroll
    for (int s = 0; s < 3; ++s) {
      const float* W = Ws[s];
      float a0 = W[r*3+0], a1 = W[r*3+1], a2 = W[r*3+2];
#pragma unroll
      for (int k = 0; k < 4; ++k)
        acc[s][k] = fmaf(a0, t[k], fmaf(a1, t[k+1], fmaf(a2, t[k+2], acc[s][k])));
    }
  }
}

// ---------- kernels ----------

__global__ void __launch_bounds__(256) k_prep(
    float* __restrict__ uo, float* __restrict__ vo, float* __restrict__ wo,
    float* __restrict__ gqu, float* __restrict__ gqv, float* __restrict__ gqw,
    float* __restrict__ ap0,
    const float* __restrict__ vu, const float* __restrict__ vv, const float* __restrict__ vw,
    const float* __restrict__ pf, const float* __restrict__ sg,
    const float* __restrict__ wx, const float* __restrict__ wy,
    const float* __restrict__ wz, const float* __restrict__ wA,
    const float* __restrict__ dtp) {
  int x0 = threadIdx.x * 4;
  int y  = blockIdx.x * 8 + threadIdx.y;
  int z  = blockIdx.y;
  bool lo = (x0 == 0), hi = (x0 == NN-4);
  int rb[9]; bool rn[9];
  prep9(z, y, rb, rn);
  float dt = dtp[0];
  int i4 = ((z*NN + y)*NN + x0) >> 2;

  float4 u4 = ((const float4*)vu)[i4];
  float4 v4 = ((const float4*)vv)[i4];
  float4 w4 = ((const float4*)vw)[i4];
  float4 s4 = ((const float4*)sg)[i4];

  float aP[4][4] = {};
  sten4<false>(pf, rb, rn, lo, hi, x0, wx, wy, wz, wA, aP, (float4*)nullptr);

  float uv[4] = {u4.x, u4.y, u4.z, u4.w};
  float vv_[4] = {v4.x, v4.y, v4.z, v4.w};
  float wv[4] = {w4.x, w4.y, w4.z, w4.w};
  float sv[4] = {s4.x, s4.y, s4.z, s4.w};
  float ou[4], ov[4], ow[4], gu[4], gv[4], gw[4];
#pragma unroll
  for (int k = 0; k < 4; ++k) {
    float rd = 1.0f / (1.0f + dt*sv[k]);
    ou[k] = uv[k]*rd; ov[k] = vv_[k]*rd; ow[k] = wv[k]*rd;
    gu[k] = ou[k] - aP[0][k]*dt;
    gv[k] = ov[k] - aP[1][k]*dt;
    gw[k] = ow[k] - aP[2][k]*dt;
  }
  ((float4*)uo)[i4]  = make_float4(ou[0], ou[1], ou[2], ou[3]);
  ((float4*)vo)[i4]  = make_float4(ov[0], ov[1], ov[2], ov[3]);
  ((float4*)wo)[i4]  = make_float4(ow[0], ow[1], ow[2], ow[3]);
  ((float4*)gqu)[i4] = make_float4(gu[0], gu[1], gu[2], gu[3]);
  ((float4*)gqv)[i4] = make_float4(gv[0], gv[1], gv[2], gv[3]);
  ((float4*)gqw)[i4] = make_float4(gw[0], gw[1], gw[2], gw[3]);
  ((float4*)ap0)[i4] = make_float4(aP[3][0], aP[3][1], aP[3][2], aP[3][3]);
}

// LDS plane-march momentum v2.
__global__ void __launch_bounds__(256) k_mom3_lds2(
    float* __restrict__ du, float* __restrict__ dv, float* __restrict__ dw,
    const float* __restrict__ su, const float* __restrict__ sv, const float* __restrict__ sw,
    const float* __restrict__ gqu, const float* __restrict__ gqv, const float* __restrict__ gqw,
    const float* __restrict__ sg,
    const float* __restrict__ wx, const float* __restrict__ wy,
    const float* __restrict__ wz, const float* __restrict__ wd,
    const float* __restrict__ dtp, float scale) {
  __shared__ float slab[3*SLAB3];
  int tid = threadIdx.y*32 + threadIdx.x;
  int x0 = threadIdx.x*4, yy = threadIdx.y;
  int y0 = blockIdx.x * YB;
  int z0 = blockIdx.y * ZSEG;
  int y  = y0 + yy;
  float dt = dtp[0];
  const float* Ws[4] = {wx, wy, wz, wd};

  float sw27 = 0.f;
#pragma unroll
  for (int j = 0; j < 27; ++j) sw27 += wd[j];

  int pk_src[NIT], pk_aux[NIT];
  stage_precompute(tid, y0, pk_src, pk_aux);

  // prologue: planes z0-1 (slot (z0+2)%3) and z0 (slot z0%3)
  stage_plane2(slab, (z0+2)%3, z0-1, su, sv, sw, pk_src, pk_aux);
  stage_plane2(slab, z0%3,     z0,   su, sv, sw, pk_src, pk_aux);

  int sm = (z0+2)%3, sc = z0%3, sp = (z0+1)%3;
  for (int z = z0; z < z0 + ZSEG; ++z) {
    stage_plane2(slab, sp, z+1, su, sv, sw, pk_src, pk_aux);
    __syncthreads();

    float aF[3][4][4] = {};
    float cen[3][4];
    const int slots[3] = {sm, sc, sp};
#pragma unroll
    for (int f = 0; f < 3; ++f) {
#pragma unroll
      for (int dz = 0; dz < 3; ++dz) {
        const float* fb = slab + (size_t)slots[dz]*SLAB3 + f*SFLD;
#pragma unroll
        for (int dy = 0; dy < 3; ++dy) {
          const float* row = fb + (yy+dy)*SLABW + x0;
          float4 A = *(const float4*)row;
          float2 B = *(const float2*)(row + 4);
          float t[6] = {A.x, A.y, A.z, A.w, B.x, B.y};
          if (dz == 1 && dy == 1) {
            cen[f][0] = t[1]; cen[f][1] = t[2]; cen[f][2] = t[3]; cen[f][3] = t[4];
          }
#pragma unroll
          for (int s = 0; s < 4; ++s) {
            const float* W = Ws[s];
            float a0 = W[(dz*3+dy)*3+0], a1 = W[(dz*3+dy)*3+1], a2 = W[(dz*3+dy)*3+2];
#pragma unroll
            for (int k = 0; k < 4; ++k)
              aF[f][s][k] = fmaf(a0, t[k], fmaf(a1, t[k+1], fmaf(a2, t[k+2], aF[f][s][k])));
          }
        }
      }
    }

    int i4 = ((z*NN + y)*NN + x0) >> 2;
    float4 gu4 = ((const float4*)gqu)[i4];
    float4 gv4 = ((const float4*)gqv)[i4];
    float4 gw4 = ((const float4*)gqw)[i4];
    float4 sg4 = ((const float4*)sg)[i4];
    float guv[4] = {gu4.x, gu4.y, gu4.z, gu4.w};
    float gvv[4] = {gv4.x, gv4.y, gv4.z, gv4.w};
    float gwv[4] = {gw4.x, gw4.y, gw4.z, gw4.w};
    float sgv[4] = {sg4.x, sg4.y, sg4.z, sg4.w};
    float ou[4], ov[4], ow[4];
#pragma unroll
    for (int k = 0; k < 4; ++k) {
      float cu = cen[0][k], cv = cen[1][k], cw = cen[2][k];
      float ku = aF[0][3][k] - 0.5f*sw27*cu;
      float kv = aF[1][3][k] - 0.5f*sw27*cv;
      float kw = aF[2][3][k] - 0.5f*sw27*cw;
      float ru = guv[k] + scale*dt*(0.001f*ku - cu*aF[0][0][k] - cv*aF[0][1][k] - cw*aF[0][2][k]);
      float rv = gvv[k] + scale*dt*(0.001f*kv - cu*aF[1][0][k] - cv*aF[1][1][k] - cw*aF[1][2][k]);
      float rw = gwv[k] + scale*dt*(0.001f*kw - cu*aF[2][0][k] - cv*aF[2][1][k] - cw*aF[2][2][k]);
      float rd = 1.0f / (1.0f + dt*sgv[k]);
      ou[k] = ru*rd; ov[k] = rv*rd; ow[k] = rw*rd;
    }
    ((float4*)du)[i4] = make_float4(ou[0], ou[1], ou[2], ou[3]);
    ((float4*)dv)[i4] = make_float4(ov[0], ov[1], ov[2], ov[3]);
    ((float4*)dw)[i4] = make_float4(ow[0], ow[1], ow[2], ow[3]);
    __syncthreads();
    int t0 = sm; sm = sc; sc = sp; sp = t0;
  }
}

// LDS plane-march divergence+residual v2.
__global__ void __launch_bounds__(256) k_bdiv_lds2(
    float* __restrict__ bb, float* __restrict__ rfine,
    const float* __restrict__ su, const float* __restrict__ sv, const float* __restrict__ sw,
    const float* __restrict__ ap0,
    const float* __restrict__ wx, const float* __restrict__ wy, const float* __restrict__ wz,
    const float* __restrict__ dtp) {
  __shared__ float slab[3*SLAB3];
  int tid = threadIdx.y*32 + threadIdx.x;
  int x0 = threadIdx.x*4, yy = threadIdx.y;
  int y0 = blockIdx.x * YB;
  int z0 = blockIdx.y * ZSEG;
  int y  = y0 + yy;
  float rdt = 1.0f / dtp[0];
  const float* Ws[3] = {wx, wy, wz};

  int pk_src[NIT], pk_aux[NIT];
  stage_precompute(tid, y0, pk_src, pk_aux);

  stage_plane2(slab, (z0+2)%3, z0-1, su, sv, sw, pk_src, pk_aux);
  stage_plane2(slab, z0%3,     z0,   su, sv, sw, pk_src, pk_aux);

  int sm = (z0+2)%3, sc = z0%3, sp = (z0+1)%3;
  for (int z = z0; z < z0 + ZSEG; ++z) {
    stage_plane2(slab, sp, z+1, su, sv, sw, pk_src, pk_aux);
    __syncthreads();

    float sacc[4] = {};
    const int slots[3] = {sm, sc, sp};
#pragma unroll
    for (int f = 0; f < 3; ++f) {
      const float* W = Ws[f];
#pragma unroll
      for (int dz = 0; dz < 3; ++dz) {
        const float* fb = slab + (size_t)slots[dz]*SLAB3 + f*SFLD;
#pragma unroll
        for (int dy = 0; dy < 3; ++dy) {
          const float* row = fb + (yy+dy)*SLABW + x0;
          float4 A = *(const float4*)row;
          float2 B = *(const float2*)(row + 4);
          float t[6] = {A.x, A.y, A.z, A.w, B.x, B.y};
          float a0 = W[(dz*3+dy)*3+0], a1 = W[(dz*3+dy)*3+1], a2 = W[(dz*3+dy)*3+2];
#pragma unroll
          for (int k = 0; k < 4; ++k)
            sacc[k] = fmaf(a0, t[k], fmaf(a1, t[k+1], fmaf(a2, t[k+2], sacc[k])));
        }
      }
    }

    int i4 = ((z*NN + y)*NN + x0) >> 2;
    float4 a4 = ((const float4*)ap0)[i4];
    float av[4] = {a4.x, a4.y, a4.z, a4.w};
    float bv[4], rv[4];
#pragma unroll
    for (int k = 0; k < 4; ++k) {
      bv[k] = -sacc[k]*rdt;
      rv[k] = av[k] - bv[k];
    }
    ((float4*)bb)[i4]    = make_float4(bv[0], bv[1], bv[2], bv[3]);
    ((float4*)rfine)[i4] = make_float4(rv[0], rv[1], rv[2], rv[3]);
    __syncthreads();
    int t0 = sm; sm = sc; sc = sp; sp = t0;
  }
}

// ---------- coarse-cell residual (it1) ----------

__device__ __forceinline__ void row4(const float* __restrict__ f, int base,
                                     bool lo, bool hi, float t[4]) {
  float2 c = *(const float2*)(f + base);
  t[0] = f[base - (lo ? 0 : 1)];
  t[1] = c.x; t[2] = c.y;
  t[3] = f[base + (hi ? 1 : 2)];
}

__device__ __forceinline__ void prep16(int Z, int Y, int rb[16], bool rn[16]) {
  int z0 = 2*Z, y0 = 2*Y;
  int zi[4] = {z0 > 0 ? z0-1 : 0, z0, z0+1, z0+2 < NN ? z0+2 : NN-1};
  int yi[4] = {y0 > 0 ? y0-1 : 0, y0, y0+1, y0+2 < NN ? y0+2 : NN-1};
  bool zo[4] = {Z == 0, false, false, Z == 63};
  bool yo[4] = {Y == 0, false, false, Y == 63};
#pragma unroll
  for (int a = 0; a < 4; ++a)
#pragma unroll
    for (int b = 0; b < 4; ++b) {
      rb[a*4+b] = (zi[a]*NN + yi[b])*NN;
      rn[a*4+b] = zo[a] | yo[b];
    }
}

template<bool NEG>
__device__ __forceinline__ void cc_acc(
    const float* __restrict__ f, const float* __restrict__ W,
    const int rb[16], const bool rn[16], bool lo, bool hi, int x0,
    float out8[8]) {
#pragma unroll
  for (int zp = 0; zp < 4; ++zp) {
    float t[4][4];
#pragma unroll
    for (int yp = 0; yp < 4; ++yp) {
      row4(f, rb[zp*4+yp] + x0, lo, hi, t[yp]);
      if (NEG) {
        bool rno = rn[zp*4+yp];
        float sr = rno ? -1.f : 1.f;
        t[yp][1] *= sr; t[yp][2] *= sr;
        t[yp][0] *= (rno | lo) ? -1.f : 1.f;
        t[yp][3] *= (rno | hi) ? -1.f : 1.f;
      }
    }
#pragma unroll
    for (int dz = 0; dz < 2; ++dz) {
      int a = zp - dz;
      if (a < 0 || a > 2) continue;
#pragma unroll
      for (int oy = 0; oy < 2; ++oy)
#pragma unroll
        for (int b = 0; b < 3; ++b) {
          const float* tr = t[oy + b];
          float w0 = W[(a*3+b)*3+0], w1 = W[(a*3+b)*3+1], w2 = W[(a*3+b)*3+2];
#pragma unroll
          for (int dx = 0; dx < 2; ++dx)
            out8[(dz*2+oy)*2+dx] =
              fmaf(w0, tr[dx], fmaf(w1, tr[dx+1], fmaf(w2, tr[dx+2], out8[(dz*2+oy)*2+dx])));
        }
    }
  }
}

__global__ void __launch_bounds__(256) k_resres1(
    float* __restrict__ rfine, float* __restrict__ rc1,
    const float* __restrict__ pf, const float* __restrict__ bb,
    const float* __restrict__ wA, const float* __restrict__ wr) {
  int i = blockIdx.x*256 + threadIdx.x;
  if (i >= 64*64*64) return;
  int X = i & 63, Y = (i >> 6) & 63, Z = i >> 12;
  bool lo = (X == 0), hi = (X == 63);
  int x0 = 2*X;
  int rb[16]; bool rn[16];
  prep16(Z, Y, rb, rn);
  float a8[8] = {};
  cc_acc<false>(pf, wA, rb, rn, lo, hi, x0, a8);
  float rsum = 0.f;
#pragma unroll
  for (int f = 0; f < 8; ++f) {
    int dz = f >> 2, dy = (f >> 1) & 1, dx = f & 1;
    int idx = ((2*Z+dz)*NN + (2*Y+dy))*NN + x0 + dx;
    float rcell = a8[f] - bb[idx];
    rfine[idx] = rcell;
    rsum = fmaf(wr[(dz*2+dy)*2+dx], rcell, rsum);
  }
  rc1[i] = rsum;
}

__global__ void __launch_bounds__(256) k_restrict(
    float* __restrict__ dst, const float* __restrict__ src,
    const float* __restrict__ wr, int no) {
  int i = blockIdx.x*256 + threadIdx.x;
  int n3 = no*no*no;
  if (i >= n3) return;
  int x = i % no; int t = i / no; int y = t % no; int z = t / no;
  int ni = 2*no;
  float s = 0.f;
#pragma unroll
  for (int a = 0; a < 2; ++a)
#pragma unroll
    for (int b = 0; b < 2; ++b)
#pragma unroll
      for (int c = 0; c < 2; ++c)
        s = fmaf(wr[(a*2+b)*2+c], src[((2*z+a)*ni + (2*y+b))*ni + (2*x+c)], s);
  dst[i] = s;
}

__device__ __forceinline__ float azb_prol(const float* __restrict__ wh, int hs, int s,
    int z, int y, int x, const float* __restrict__ wA) {
  float acc = 0.f;
#pragma unroll
  for (int a = 0; a < 3; ++a) { int zz = z + a - 1; if ((unsigned)zz >= (unsigned)s) continue;
#pragma unroll
    for (int b = 0; b < 3; ++b) { int yy = y + b - 1; if ((unsigned)yy >= (unsigned)s) continue;
#pragma unroll
      for (int c = 0; c < 3; ++c) { int xx = x + c - 1; if ((unsigned)xx >= (unsigned)s) continue;
        acc = fmaf(wA[(a*3+b)*3+c], wh[((zz>>1)*hs + (yy>>1))*hs + (xx>>1)], acc);
      } } }
  return acc;
}

__global__ void __launch_bounds__(512) k_mg_small(
    float* __restrict__ w16, float* __restrict__ r_o,
    const float* __restrict__ rc2,
    const float* __restrict__ wA, const float* __restrict__ wr) {
  __shared__ float r16[4096];
  __shared__ float r8[512];
  __shared__ float r4[64];
  __shared__ float r2[8];
  __shared__ float wa[512];
  __shared__ float wb[64];
  __shared__ float scal[2];
  int tid = threadIdx.x;
  float diag = wA[13];
  float wrl[8];
#pragma unroll
  for (int j = 0; j < 8; ++j) wrl[j] = wr[j];

  for (int j = tid; j < 4096; j += 512) {
    int x = j & 15, y = (j >> 4) & 15, z = j >> 8;
    float s = 0.f;
#pragma unroll
    for (int a = 0; a < 2; ++a)
#pragma unroll
      for (int b = 0; b < 2; ++b)
#pragma unroll
        for (int c = 0; c < 2; ++c)
          s = fmaf(wrl[(a*2+b)*2+c], rc2[((2*z+a)*32 + (2*y+b))*32 + (2*x+c)], s);
    r16[j] = s;
  }
  __syncthreads();
  {
    int j = tid;
    int x = j & 7, y = (j >> 3) & 7, z = j >> 6;
    float s = 0.f;
#pragma unroll
    for (int a = 0; a < 2; ++a)
#pragma unroll
      for (int b = 0; b < 2; ++b)
#pragma unroll
        for (int c = 0; c < 2; ++c)
          s = fmaf(wrl[(a*2+b)*2+c], r16[((2*z+a)*16 + (2*y+b))*16 + (2*x+c)], s);
    r8[j] = s;
  }
  __syncthreads();
  if (tid < 64) {
    int x = tid & 3, y = (tid >> 2) & 3, z = tid >> 4;
    float s = 0.f;
#pragma unroll
    for (int a = 0; a < 2; ++a)
#pragma unroll
      for (int b = 0; b < 2; ++b)
#pragma unroll
        for (int c = 0; c < 2; ++c)
          s = fmaf(wrl[(a*2+b)*2+c], r8[((2*z+a)*8 + (2*y+b))*8 + (2*x+c)], s);
    r4[tid] = s;
  }
  __syncthreads();
  if (tid < 8) {
    int x = tid & 1, y = (tid >> 1) & 1, z = tid >> 2;
    float s = 0.f;
#pragma unroll
    for (int a = 0; a < 2; ++a)
#pragma unroll
      for (int b = 0; b < 2; ++b)
#pragma unroll
        for (int c = 0; c < 2; ++c)
          s = fmaf(wrl[(a*2+b)*2+c], r4[((2*z+a)*4 + (2*y+b))*4 + (2*x+c)], s);
    r2[tid] = s;
  }
  __syncthreads();
  if (tid == 0) {
    float s = 0.f;
#pragma unroll
    for (int j = 0; j < 8; ++j) s = fmaf(wrl[j], r2[j], s);
    scal[0] = s;
    r_o[0] = s;
    scal[1] = s / diag;
  }
  __syncthreads();
  if (tid < 8) {
    int x = tid & 1, y = (tid >> 1) & 1, z = tid >> 2;
    float wp = scal[1];
    float az = azb_prol(&scal[1], 1, 2, z, y, x, wA);
    wa[tid] = wp - az/diag + r2[tid]/diag;
  }
  __syncthreads();
  if (tid < 64) {
    int x = tid & 3, y = (tid >> 2) & 3, z = tid >> 4;
    float wp = wa[((z>>1)*2 + (y>>1))*2 + (x>>1)];
    float az = azb_prol(wa, 2, 4, z, y, x, wA);
    wb[tid] = wp - az/diag + r4[tid]/diag;
  }
  __syncthreads();
  {
    int j = tid;
    int x = j & 7, y = (j >> 3) & 7, z = j >> 6;
    float wp = wb[((z>>1)*4 + (y>>1))*4 + (x>>1)];
    float az = azb_prol(wb, 4, 8, z, y, x, wA);
    wa[j] = wp - az/diag + r8[j]/diag;
  }
  __syncthreads();
  for (int j = tid; j < 4096; j += 512) {
    int x = j & 15, y = (j >> 4) & 15, z = j >> 8;
    float wp = wa[((z>>1)*8 + (y>>1))*8 + (x>>1)];
    float az = azb_prol(wa, 8, 16, z, y, x, wA);
    w16[j] = wp - az/diag + r16[j]/diag;
  }
}

__global__ void __launch_bounds__(256) k_coarse_step(
    float* __restrict__ wout, const float* __restrict__ wh,
    const float* __restrict__ rl, const float* __restrict__ wA, int s) {
  int i = blockIdx.x*256 + threadIdx.x;
  int n3 = s*s*s;
  if (i >= n3) return;
  int x = i % s; int t = i / s; int y = t % s; int z = t / s;
  int hs = s >> 1;
  float diag = wA[13];
  float wp = wh[((z>>1)*hs + (y>>1))*hs + (x>>1)];
  float az = azb_prol(wh, hs, s, z, y, x, wA);
  wout[i] = wp - az/diag + rl[i]/diag;
}

__global__ void __launch_bounds__(256) k_pupd4(
    float* __restrict__ pdst, float* __restrict__ wmgo,
    const float* __restrict__ psrc, const float* __restrict__ rfine,
    const float* __restrict__ w64, const float* __restrict__ wA, int writeWmg) {
  int i4 = blockIdx.x*256 + threadIdx.x;
  if (i4 >= NF/4) return;
  int i = i4*4;
  int x = i & (NN-1); int t = i >> 7; int y = t & (NN-1); int z = t >> 7;
  float rdiag = 1.0f / wA[13];
  float2 w2 = *(const float2*)(w64 + ((size_t)(z>>1)*64 + (y>>1))*64 + (x>>1));
  float4 ps = ((const float4*)psrc)[i4];
  float4 rf = ((const float4*)rfine)[i4];
  float4 o = make_float4(ps.x - w2.x - rf.x*rdiag,
                         ps.y - w2.x - rf.y*rdiag,
                         ps.z - w2.y - rf.z*rdiag,
                         ps.w - w2.y - rf.w*rdiag);
  ((float4*)pdst)[i4] = o;
  if (writeWmg) ((float4*)wmgo)[i4] = make_float4(w2.x, w2.x, w2.y, w2.y);
}

__global__ void __launch_bounds__(256) k_proj3(
    float* __restrict__ u, float* __restrict__ v, float* __restrict__ w,
    const float* __restrict__ pf, const float* __restrict__ sg,
    const float* __restrict__ wx, const float* __restrict__ wy,
    const float* __restrict__ wz, const float* __restrict__ dtp) {
  int x0 = threadIdx.x * 4;
  int y  = blockIdx.x * 8 + threadIdx.y;
  int z  = blockIdx.y;
  bool lo = (x0 == 0), hi = (x0 == NN-4);
  int rb[9]; bool rn[9];
  prep9(z, y, rb, rn);
  float aP[3][4] = {};
  sten_p3(pf, rb, lo, hi, x0, wx, wy, wz, aP);
  float dt = dtp[0];
  int i4 = ((z*NN + y)*NN + x0) >> 2;
  float4 u4 = ((const float4*)u)[i4];
  float4 v4 = ((const float4*)v)[i4];
  float4 w4 = ((const float4*)w)[i4];
  float4 sg4 = ((const float4*)sg)[i4];
  float ua[4] = {u4.x, u4.y, u4.z, u4.w};
  float va[4] = {v4.x, v4.y, v4.z, v4.w};
  float wa[4] = {w4.x, w4.y, w4.z, w4.w};
  float sa[4] = {sg4.x, sg4.y, sg4.z, sg4.w};
  float ou[4], ov[4], ow[4];
#pragma unroll
  for (int k = 0; k < 4; ++k) {
    float rd = 1.0f / (1.0f + dt*sa[k]);
    ou[k] = (ua[k] - aP[0][k]*dt)*rd;
    ov[k] = (va[k] - aP[1][k]*dt)*rd;
    ow[k] = (wa[k] - aP[2][k]*dt)*rd;
  }
  ((float4*)u)[i4] = make_float4(ou[0], ou[1], ou[2], ou[3]);
  ((float4*)v)[i4] = make_float4(ov[0], ov[1], ov[2], ov[3]);
  ((float4*)w)[i4] = make_float4(ow[0], ow[1], ow[2], ow[3]);
}

// ---------- launch ----------

extern "C" void kernel_launch(void* const* d_in, const int* in_sizes, int n_in,
                              void* d_out, int out_size, void* d_ws, size_t ws_size,
                              hipStream_t stream) {
  const float* values_u = (const float*)d_in[0];
  const float* values_v = (const float*)d_in[1];
  const float* values_w = (const float*)d_in[2];
  const float* values_p = (const float*)d_in[3];
  const float* sigma    = (const float*)d_in[4];
  const float* wx       = (const float*)d_in[5];
  const float* wy       = (const float*)d_in[6];
  const float* wz       = (const float*)d_in[7];
  const float* wd       = (const float*)d_in[8];
  const float* wA       = (const float*)d_in[9];
  const float* wr       = (const float*)d_in[10];
  const float* dtp      = (const float*)d_in[11];

  float* out   = (float*)d_out;
  float* u_o   = out;
  float* v_o   = out + (size_t)NF;
  float* w_o   = out + (size_t)2*NF;
  float* p_o   = out + (size_t)3*NF;
  float* wmg_o = out + (size_t)4*NF;
  float* r_o   = out + (size_t)5*NF;

  float* ws    = (float*)d_ws;
  float* f0    = ws;
  float* f1    = f0 + (size_t)NF;
  float* f2    = f1 + (size_t)NF;
  float* bws   = f2 + (size_t)NF;
  float* rfine = bws + (size_t)NF;
  float* pbuf  = rfine + (size_t)NF;
  float* gqu   = pbuf + (size_t)NF;
  float* gqv   = gqu + (size_t)NF;
  float* gqw   = gqv + (size_t)NF;
  float* ap0   = gqw + (size_t)NF;
  float* rc1   = ap0 + (size_t)NF;       // 64^3
  float* rc2   = rc1 + 262144;           // 32^3
  float* w16   = rc2 + 32768;            // 16^3
  float* w32   = w16 + 4096;             // 32^3
  float* w64   = w32 + 32768;            // 64^3

  const int TB = 256;
  dim3 blkS(32, 8, 1);
  dim3 grdS(16, 128, 1);   // plane-major for non-LDS stencil kernels
  dim3 blkM(32, 8, 1);
  dim3 grdM(16, 64, 1);    // LDS plane-march: 16 ybands x 64 zsegs (ZSEG=2)

  k_prep<<<grdS, blkS, 0, stream>>>(u_o, v_o, w_o, gqu, gqv, gqw, ap0,
                                    values_u, values_v, values_w, values_p, sigma,
                                    wx, wy, wz, wA, dtp);
  k_mom3_lds2<<<grdM, blkM, 0, stream>>>(f0, f1, f2, u_o, v_o, w_o, gqu, gqv, gqw,
                                         sigma, wx, wy, wz, wd, dtp, 0.5f);
  k_mom3_lds2<<<grdM, blkM, 0, stream>>>(u_o, v_o, w_o, f0, f1, f2, gqu, gqv, gqw,
                                         sigma, wx, wy, wz, wd, dtp, 1.0f);

  // it 0
  k_bdiv_lds2<<<grdM, blkM, 0, stream>>>(bws, rfine, u_o, v_o, w_o, ap0,
                                         wx, wy, wz, dtp);
  k_restrict<<<1024, TB, 0, stream>>>(rc1, rfine, wr, 64);
  k_restrict<<<128, TB, 0, stream>>>(rc2, rc1, wr, 32);
  k_mg_small<<<1, 512, 0, stream>>>(w16, r_o, rc2, wA, wr);
  k_coarse_step<<<128, TB, 0, stream>>>(w32, w16, rc2, wA, 32);
  k_coarse_step<<<1024, TB, 0, stream>>>(w64, w32, rc1, wA, 64);
  k_pupd4<<<NF/4/TB, TB, 0, stream>>>(pbuf, wmg_o, values_p, rfine, w64, wA, 0);

  // it 1
  k_resres1<<<1024, TB, 0, stream>>>(rfine, rc1, pbuf, bws, wA, wr);
  k_restrict<<<128, TB, 0, stream>>>(rc2, rc1, wr, 32);
  k_mg_small<<<1, 512, 0, stream>>>(w16, r_o, rc2, wA, wr);
  k_coarse_step<<<128, TB, 0, stream>>>(w32, w16, rc2, wA, 32);
  k_coarse_step<<<1024, TB, 0, stream>>>(w64, w32, rc1, wA, 64);
  k_pupd4<<<NF/4/TB, TB, 0, stream>>>(p_o, wmg_o, pbuf, rfine, w64, wA, 1);

  k_proj3<<<grdS, blkS, 0, stream>>>(u_o, v_o, w_o, p_o, sigma, wx, wy, wz, dtp);
}

// Round 10
// 221.991 us; speedup vs baseline: 1.4493x; 1.4493x over previous
//
#include <hip/hip_runtime.h>
#include <stdint.h>

// AI4Urban fused CFD timestep on 128^3 f32 grid.
// Round 10: heavy 3-field stencil kernels use __builtin_amdgcn_global_load_lds
// (direct L2->LDS DMA, bypassing the measured ~7.3 TB/s L2->L1 fill wall that
// pinned every sweep at ~15us). 4-slot LDS ring, fully unrolled z-steps so
// slot bases are compile-time; linear 128-float rows (intrinsic requires
// linear dest); clamp/sign at consume. Everything else = r7 (226us best).

#define NN 128
#define NF (NN*NN*NN)   // 2097152

#define YB 8
#define ZSEG 4
#define RPF 10                 // rows per field-plane (YB+2)
#define RW 128                 // floats per row
#define FPL (RPF*RW)           // 1280
#define PL3 (3*FPL)            // 3840 floats per plane slot
// slab: 4 slots * 3840 * 4B = 61440 B -> 2 blocks/CU

// ---------- global_load_lds staging ----------

// Stage plane zp (logical [-1..128]) of {su,sv,sw} into ring slot `slot`.
// 15 calls (3 fields x 5), each covers 2 rows (lanes 0-31 / 32-63).
// Rows are raw clamped values; sign handled at consume.
__device__ __forceinline__ void stage_gld(
    float* __restrict__ slab, int slot, int zp, int y0,
    const float* __restrict__ su, const float* __restrict__ sv,
    const float* __restrict__ sw, int wave, int lane) {
  int gz = min(max(zp, 0), NN-1);
  int halfsel = lane >> 5;            // 0: even row, 1: odd row
  int xoff = (lane & 31) << 2;        // float index within row
  int cidx = 0;
#pragma unroll
  for (int f = 0; f < 3; ++f) {
    const float* fp = (f == 0) ? su : ((f == 1) ? sv : sw);
#pragma unroll
    for (int q = 0; q < 5; ++q, ++cidx) {
      if ((cidx & 3) != wave) continue;
      int r = 2*q + halfsel;
      int gy = min(max(y0 - 1 + r, 0), NN-1);
      const float* gp = fp + ((size_t)(gz*NN + gy) << 7) + xoff;
      float* lp = slab + (size_t)slot*PL3 + f*FPL + 2*q*RW;   // wave-uniform
      __builtin_amdgcn_global_load_lds(
          (const __attribute__((address_space(1))) uint32_t*)gp,
          (__attribute__((address_space(3))) uint32_t*)lp, 16, 0, 0);
    }
  }
}

// ---------- r7 helpers (unchanged) ----------

__device__ __forceinline__ void prep9(int z, int y, int rb[9], bool rn[9]) {
  int zi[3] = {z > 0 ? z-1 : 0, z, z < NN-1 ? z+1 : NN-1};
  int yi[3] = {y > 0 ? y-1 : 0, y, y < NN-1 ? y+1 : NN-1};
  bool zo[3] = {z == 0, false, z == NN-1};
  bool yo[3] = {y == 0, false, y == NN-1};
#pragma unroll
  for (int a = 0; a < 3; ++a)
#pragma unroll
    for (int b = 0; b < 3; ++b) {
      rb[a*3+b] = (zi[a]*NN + yi[b])*NN;
      rn[a*3+b] = zo[a] | yo[b];
    }
}

template<bool NEG>
__device__ __forceinline__ void sten4(
    const float* __restrict__ f, const int rb[9], const bool rn[9],
    bool lo, bool hi, int x0,
    const float* __restrict__ w0p, const float* __restrict__ w1p,
    const float* __restrict__ w2p, const float* __restrict__ w3p,
    float acc[4][4], float4* center) {
  const float* const Ws[4] = {w0p, w1p, w2p, w3p};
#pragma unroll
  for (int r = 0; r < 9; ++r) {
    int base = rb[r] + x0;
    float4 c = *(const float4*)(f + base);
    float m1 = f[base - (lo ? 0 : 1)];
    float p4 = f[base + (hi ? 3 : 4)];
    if (NEG) {
      float sr = rn[r] ? -1.f : 1.f;
      m1 *= (rn[r] | lo) ? -1.f : 1.f;
      p4 *= (rn[r] | hi) ? -1.f : 1.f;
      c.x *= sr; c.y *= sr; c.z *= sr; c.w *= sr;
    }
    if (r == 4 && center) *center = c;
    float t[6] = {m1, c.x, c.y, c.z, c.w, p4};
#pragma unroll
    for (int s = 0; s < 4; ++s) {
      const float* W = Ws[s];
      float a0 = W[r*3+0], a1 = W[r*3+1], a2 = W[r*3+2];
#pragma unroll
      for (int k = 0; k < 4; ++k)
        acc[s][k] = fmaf(a0, t[k], fmaf(a1, t[k+1], fmaf(a2, t[k+2], acc[s][k])));
    }
  }
}

__device__ __forceinline__ void sten_p3(
    const float* __restrict__ f, const int rb[9],
    bool lo, bool hi, int x0,
    const float* __restrict__ w0p, const float* __restrict__ w1p,
    const float* __restrict__ w2p, float acc[3][4]) {
  const float* const Ws[3] = {w0p, w1p, w2p};
#pragma unroll
  for (int r = 0; r < 9; ++r) {
    int base = rb[r] + x0;
    float4 c = *(const float4*)(f + base);
    float m1 = f[base - (lo ? 0 : 1)];
    float p4 = f[base + (hi ? 3 : 4)];
    float t[6] = {m1, c.x, c.y, c.z, c.w, p4};
#pragma unroll
    for (int s = 0; s < 3; ++s) {
      const float* W = Ws[s];
      float a0 = W[r*3+0], a1 = W[r*3+1], a2 = W[r*3+2];
#pragma unroll
      for (int k = 0; k < 4; ++k)
        acc[s][k] = fmaf(a0, t[k], fmaf(a1, t[k+1], fmaf(a2, t[k+2], acc[s][k])));
    }
  }
}

// ---------- kernels ----------

__global__ void __launch_bounds__(256) k_prep(
    float* __restrict__ uo, float* __restrict__ vo, float* __restrict__ wo,
    float* __restrict__ gqu, float* __restrict__ gqv, float* __restrict__ gqw,
    float* __restrict__ ap0,
    const float* __restrict__ vu, const float* __restrict__ vv, const float* __restrict__ vw,
    const float* __restrict__ pf, const float* __restrict__ sg,
    const float* __restrict__ wx, const float* __restrict__ wy,
    const float* __restrict__ wz, const float* __restrict__ wA,
    const float* __restrict__ dtp) {
  int x0 = threadIdx.x * 4;
  int y  = blockIdx.x * 8 + threadIdx.y;
  int z  = blockIdx.y;
  bool lo = (x0 == 0), hi = (x0 == NN-4);
  int rb[9]; bool rn[9];
  prep9(z, y, rb, rn);
  float dt = dtp[0];
  int i4 = ((z*NN + y)*NN + x0) >> 2;

  float4 u4 = ((const float4*)vu)[i4];
  float4 v4 = ((const float4*)vv)[i4];
  float4 w4 = ((const float4*)vw)[i4];
  float4 s4 = ((const float4*)sg)[i4];

  float aP[4][4] = {};
  sten4<false>(pf, rb, rn, lo, hi, x0, wx, wy, wz, wA, aP, (float4*)nullptr);

  float uv[4] = {u4.x, u4.y, u4.z, u4.w};
  float vv_[4] = {v4.x, v4.y, v4.z, v4.w};
  float wv[4] = {w4.x, w4.y, w4.z, w4.w};
  float sv[4] = {s4.x, s4.y, s4.z, s4.w};
  float ou[4], ov[4], ow[4], gu[4], gv[4], gw[4];
#pragma unroll
  for (int k = 0; k < 4; ++k) {
    float rd = 1.0f / (1.0f + dt*sv[k]);
    ou[k] = uv[k]*rd; ov[k] = vv_[k]*rd; ow[k] = wv[k]*rd;
    gu[k] = ou[k] - aP[0][k]*dt;
    gv[k] = ov[k] - aP[1][k]*dt;
    gw[k] = ow[k] - aP[2][k]*dt;
  }
  ((float4*)uo)[i4]  = make_float4(ou[0], ou[1], ou[2], ou[3]);
  ((float4*)vo)[i4]  = make_float4(ov[0], ov[1], ov[2], ov[3]);
  ((float4*)wo)[i4]  = make_float4(ow[0], ow[1], ow[2], ow[3]);
  ((float4*)gqu)[i4] = make_float4(gu[0], gu[1], gu[2], gu[3]);
  ((float4*)gqv)[i4] = make_float4(gv[0], gv[1], gv[2], gv[3]);
  ((float4*)gqw)[i4] = make_float4(gw[0], gw[1], gw[2], gw[3]);
  ((float4*)ap0)[i4] = make_float4(aP[3][0], aP[3][1], aP[3][2], aP[3][3]);
}

// Consume a staged field-plane row set: accumulate 4 conv sets for field f.
// Slots sm,sc,sp must be compile-time constants after inlining.
template<bool NEG>
__device__ __forceinline__ void consume_field(
    const float* __restrict__ slab, int sm, int sc, int sp, int f,
    int yy, int x0, bool lo, bool hi,
    const bool zon[3], const bool yon[3],
    const float* __restrict__ wx, const float* __restrict__ wy,
    const float* __restrict__ wz, const float* __restrict__ wd,
    float acc[4][4], float cen[4]) {
  const float* const Ws[4] = {wx, wy, wz, wd};
  const int slots[3] = {sm, sc, sp};
#pragma unroll
  for (int dz = 0; dz < 3; ++dz) {
    const float* fb = slab + (size_t)slots[dz]*PL3 + f*FPL;
#pragma unroll
    for (int dy = 0; dy < 3; ++dy) {
      const float* row = fb + (yy+dy)*RW;
      float4 c = *(const float4*)(row + x0);
      float m1 = lo ? c.x : row[x0-1];
      float p4 = hi ? c.w : row[x0+4];
      if (NEG) {
        bool rno = zon[dz] | yon[dy];
        float sr = rno ? -1.f : 1.f;
        m1 *= (rno | lo) ? -1.f : 1.f;
        p4 *= (rno | hi) ? -1.f : 1.f;
        c.x *= sr; c.y *= sr; c.z *= sr; c.w *= sr;
      }
      if (dz == 1 && dy == 1) {
        cen[0] = c.x; cen[1] = c.y; cen[2] = c.z; cen[3] = c.w;
      }
      float t[6] = {m1, c.x, c.y, c.z, c.w, p4};
#pragma unroll
      for (int s = 0; s < 4; ++s) {
        const float* W = Ws[s];
        float a0 = W[(dz*3+dy)*3+0], a1 = W[(dz*3+dy)*3+1], a2 = W[(dz*3+dy)*3+2];
#pragma unroll
        for (int k = 0; k < 4; ++k)
          acc[s][k] = fmaf(a0, t[k], fmaf(a1, t[k+1], fmaf(a2, t[k+2], acc[s][k])));
      }
    }
  }
}

// Momentum via global_load_lds staging.
__global__ void __launch_bounds__(256) k_mom3_gld(
    float* __restrict__ du, float* __restrict__ dv, float* __restrict__ dw,
    const float* __restrict__ su, const float* __restrict__ sv, const float* __restrict__ sw,
    const float* __restrict__ gqu, const float* __restrict__ gqv, const float* __restrict__ gqw,
    const float* __restrict__ sg,
    const float* __restrict__ wx, const float* __restrict__ wy,
    const float* __restrict__ wz, const float* __restrict__ wd,
    const float* __restrict__ dtp, float scale) {
  __shared__ float slab[4*PL3];
  int tid  = threadIdx.y*32 + threadIdx.x;
  int wave = tid >> 6;
  int lane = tid & 63;
  int x0 = threadIdx.x*4, yy = threadIdx.y;
  int y0 = blockIdx.x * YB;
  int z0 = blockIdx.y * ZSEG;           // multiple of 4
  int y  = y0 + yy;
  bool lo = (x0 == 0), hi = (x0 == NN-4);
  float dt = dtp[0];

  float sw27 = 0.f;
#pragma unroll
  for (int j = 0; j < 27; ++j) sw27 += wd[j];

  bool yon[3];
  yon[0] = (y == 0); yon[1] = false; yon[2] = (y == NN-1);

  // prologue: plane z0-1 -> slot 3, plane z0 -> slot 0
  stage_gld(slab, 3, z0-1, y0, su, sv, sw, wave, lane);
  stage_gld(slab, 0, z0,   y0, su, sv, sw, wave, lane);

#pragma unroll
  for (int j = 0; j < ZSEG; ++j) {
    stage_gld(slab, (j+1)&3, z0+j+1, y0, su, sv, sw, wave, lane);
    __syncthreads();
    int z = z0 + j;
    bool zon[3];
    zon[0] = (z == 0); zon[1] = false; zon[2] = (z == NN-1);
    const int sm = (j+3)&3, sc = j&3, sp = (j+1)&3;

    float aU[4][4] = {}, aV[4][4] = {}, aW[4][4] = {};
    float cu4[4], cv4[4], cw4[4];
    consume_field<true >(slab, sm, sc, sp, 0, yy, x0, lo, hi, zon, yon,
                         wx, wy, wz, wd, aU, cu4);
    consume_field<false>(slab, sm, sc, sp, 1, yy, x0, lo, hi, zon, yon,
                         wx, wy, wz, wd, aV, cv4);
    consume_field<false>(slab, sm, sc, sp, 2, yy, x0, lo, hi, zon, yon,
                         wx, wy, wz, wd, aW, cw4);

    int i4 = ((z*NN + y)*NN + x0) >> 2;
    float4 gu4 = ((const float4*)gqu)[i4];
    float4 gv4 = ((const float4*)gqv)[i4];
    float4 gw4 = ((const float4*)gqw)[i4];
    float4 sg4 = ((const float4*)sg)[i4];
    float guv[4] = {gu4.x, gu4.y, gu4.z, gu4.w};
    float gvv[4] = {gv4.x, gv4.y, gv4.z, gv4.w};
    float gwv[4] = {gw4.x, gw4.y, gw4.z, gw4.w};
    float sgv[4] = {sg4.x, sg4.y, sg4.z, sg4.w};
    float ou[4], ov[4], ow[4];
#pragma unroll
    for (int k = 0; k < 4; ++k) {
      float cu = cu4[k], cv = cv4[k], cw = cw4[k];
      float ku = aU[3][k] - 0.5f*sw27*cu;
      float kv = aV[3][k] - 0.5f*sw27*cv;
      float kw = aW[3][k] - 0.5f*sw27*cw;
      float ru = guv[k] + scale*dt*(0.001f*ku - cu*aU[0][k] - cv*aU[1][k] - cw*aU[2][k]);
      float rv = gvv[k] + scale*dt*(0.001f*kv - cu*aV[0][k] - cv*aV[1][k] - cw*aV[2][k]);
      float rw = gwv[k] + scale*dt*(0.001f*kw - cu*aW[0][k] - cv*aW[1][k] - cw*aW[2][k]);
      float rd = 1.0f / (1.0f + dt*sgv[k]);
      ou[k] = ru*rd; ov[k] = rv*rd; ow[k] = rw*rd;
    }
    ((float4*)du)[i4] = make_float4(ou[0], ou[1], ou[2], ou[3]);
    ((float4*)dv)[i4] = make_float4(ov[0], ov[1], ov[2], ov[3]);
    ((float4*)dw)[i4] = make_float4(ow[0], ow[1], ow[2], ow[3]);
  }
}

// Divergence + residual via global_load_lds staging.
__global__ void __launch_bounds__(256) k_bdiv_gld(
    float* __restrict__ bb, float* __restrict__ rfine,
    const float* __restrict__ su, const float* __restrict__ sv, const float* __restrict__ sw,
    const float* __restrict__ ap0,
    const float* __restrict__ wx, const float* __restrict__ wy, const float* __restrict__ wz,
    const float* __restrict__ dtp) {
  __shared__ float slab[4*PL3];
  int tid  = threadIdx.y*32 + threadIdx.x;
  int wave = tid >> 6;
  int lane = tid & 63;
  int x0 = threadIdx.x*4, yy = threadIdx.y;
  int y0 = blockIdx.x * YB;
  int z0 = blockIdx.y * ZSEG;
  int y  = y0 + yy;
  bool lo = (x0 == 0), hi = (x0 == NN-4);
  float rdt = 1.0f / dtp[0];

  bool yon[3];
  yon[0] = (y == 0); yon[1] = false; yon[2] = (y == NN-1);

  stage_gld(slab, 3, z0-1, y0, su, sv, sw, wave, lane);
  stage_gld(slab, 0, z0,   y0, su, sv, sw, wave, lane);

#pragma unroll
  for (int j = 0; j < ZSEG; ++j) {
    stage_gld(slab, (j+1)&3, z0+j+1, y0, su, sv, sw, wave, lane);
    __syncthreads();
    int z = z0 + j;
    bool zon[3];
    zon[0] = (z == 0); zon[1] = false; zon[2] = (z == NN-1);
    const int sm = (j+3)&3, sc = j&3, sp = (j+1)&3;
    const int slots[3] = {sm, sc, sp};
    const float* const Ws[3] = {wx, wy, wz};

    float sacc[4] = {};
#pragma unroll
    for (int f = 0; f < 3; ++f) {
      const float* W = Ws[f];
#pragma unroll
      for (int dz = 0; dz < 3; ++dz) {
        const float* fb = slab + (size_t)slots[dz]*PL3 + f*FPL;
#pragma unroll
        for (int dy = 0; dy < 3; ++dy) {
          const float* row = fb + (yy+dy)*RW;
          float4 c = *(const float4*)(row + x0);
          float m1 = lo ? c.x : row[x0-1];
          float p4 = hi ? c.w : row[x0+4];
          if (f == 0) {
            bool rno = zon[dz] | yon[dy];
            float sr = rno ? -1.f : 1.f;
            m1 *= (rno | lo) ? -1.f : 1.f;
            p4 *= (rno | hi) ? -1.f : 1.f;
            c.x *= sr; c.y *= sr; c.z *= sr; c.w *= sr;
          }
          float t[6] = {m1, c.x, c.y, c.z, c.w, p4};
          float a0 = W[(dz*3+dy)*3+0], a1 = W[(dz*3+dy)*3+1], a2 = W[(dz*3+dy)*3+2];
#pragma unroll
          for (int k = 0; k < 4; ++k)
            sacc[k] = fmaf(a0, t[k], fmaf(a1, t[k+1], fmaf(a2, t[k+2], sacc[k])));
        }
      }
    }

    int i4 = ((z*NN + y)*NN + x0) >> 2;
    float4 a4 = ((const float4*)ap0)[i4];
    float av[4] = {a4.x, a4.y, a4.z, a4.w};
    float bv[4], rv[4];
#pragma unroll
    for (int k = 0; k < 4; ++k) {
      bv[k] = -sacc[k]*rdt;
      rv[k] = av[k] - bv[k];
    }
    ((float4*)bb)[i4]    = make_float4(bv[0], bv[1], bv[2], bv[3]);
    ((float4*)rfine)[i4] = make_float4(rv[0], rv[1], rv[2], rv[3]);
  }
}

// ---------- coarse-cell residual (it1) + MG chain (r7) ----------

__device__ __forceinline__ void row4g(const float* __restrict__ f, int base,
                                      bool lo, bool hi, float t[4]) {
  float2 c = *(const float2*)(f + base);
  t[0] = f[base - (lo ? 0 : 1)];
  t[1] = c.x; t[2] = c.y;
  t[3] = f[base + (hi ? 1 : 2)];
}

__device__ __forceinline__ void prep16(int Z, int Y, int rb[16], bool rn[16]) {
  int z0 = 2*Z, y0 = 2*Y;
  int zi[4] = {z0 > 0 ? z0-1 : 0, z0, z0+1, z0+2 < NN ? z0+2 : NN-1};
  int yi[4] = {y0 > 0 ? y0-1 : 0, y0, y0+1, y0+2 < NN ? y0+2 : NN-1};
  bool zo[4] = {Z == 0, false, false, Z == 63};
  bool yo[4] = {Y == 0, false, false, Y == 63};
#pragma unroll
  for (int a = 0; a < 4; ++a)
#pragma unroll
    for (int b = 0; b < 4; ++b) {
      rb[a*4+b] = (zi[a]*NN + yi[b])*NN;
      rn[a*4+b] = zo[a] | yo[b];
    }
}

template<bool NEG>
__device__ __forceinline__ void cc_acc(
    const float* __restrict__ f, const float* __restrict__ W,
    const int rb[16], const bool rn[16], bool lo, bool hi, int x0,
    float out8[8]) {
#pragma unroll
  for (int zp = 0; zp < 4; ++zp) {
    float t[4][4];
#pragma unroll
    for (int yp = 0; yp < 4; ++yp) {
      row4g(f, rb[zp*4+yp] + x0, lo, hi, t[yp]);
      if (NEG) {
        bool rno = rn[zp*4+yp];
        float sr = rno ? -1.f : 1.f;
        t[yp][1] *= sr; t[yp][2] *= sr;
        t[yp][0] *= (rno | lo) ? -1.f : 1.f;
        t[yp][3] *= (rno | hi) ? -1.f : 1.f;
      }
    }
#pragma unroll
    for (int dz = 0; dz < 2; ++dz) {
      int a = zp - dz;
      if (a < 0 || a > 2) continue;
#pragma unroll
      for (int oy = 0; oy < 2; ++oy)
#pragma unroll
        for (int b = 0; b < 3; ++b) {
          const float* tr = t[oy + b];
          float w0 = W[(a*3+b)*3+0], w1 = W[(a*3+b)*3+1], w2 = W[(a*3+b)*3+2];
#pragma unroll
          for (int dx = 0; dx < 2; ++dx)
            out8[(dz*2+oy)*2+dx] =
              fmaf(w0, tr[dx], fmaf(w1, tr[dx+1], fmaf(w2, tr[dx+2], out8[(dz*2+oy)*2+dx])));
        }
    }
  }
}

__global__ void __launch_bounds__(256) k_resres1(
    float* __restrict__ rfine, float* __restrict__ rc1,
    const float* __restrict__ pf, const float* __restrict__ bb,
    const float* __restrict__ wA, const float* __restrict__ wr) {
  int i = blockIdx.x*256 + threadIdx.x;
  if (i >= 64*64*64) return;
  int X = i & 63, Y = (i >> 6) & 63, Z = i >> 12;
  bool lo = (X == 0), hi = (X == 63);
  int x0 = 2*X;
  int rb[16]; bool rn[16];
  prep16(Z, Y, rb, rn);
  float a8[8] = {};
  cc_acc<false>(pf, wA, rb, rn, lo, hi, x0, a8);
  float rsum = 0.f;
#pragma unroll
  for (int f = 0; f < 8; ++f) {
    int dz = f >> 2, dy = (f >> 1) & 1, dx = f & 1;
    int idx = ((2*Z+dz)*NN + (2*Y+dy))*NN + x0 + dx;
    float rcell = a8[f] - bb[idx];
    rfine[idx] = rcell;
    rsum = fmaf(wr[(dz*2+dy)*2+dx], rcell, rsum);
  }
  rc1[i] = rsum;
}

__global__ void __launch_bounds__(256) k_restrict(
    float* __restrict__ dst, const float* __restrict__ src,
    const float* __restrict__ wr, int no) {
  int i = blockIdx.x*256 + threadIdx.x;
  int n3 = no*no*no;
  if (i >= n3) return;
  int x = i % no; int t = i / no; int y = t % no; int z = t / no;
  int ni = 2*no;
  float s = 0.f;
#pragma unroll
  for (int a = 0; a < 2; ++a)
#pragma unroll
    for (int b = 0; b < 2; ++b)
#pragma unroll
      for (int c = 0; c < 2; ++c)
        s = fmaf(wr[(a*2+b)*2+c], src[((2*z+a)*ni + (2*y+b))*ni + (2*x+c)], s);
  dst[i] = s;
}

__device__ __forceinline__ float azb_prol(const float* __restrict__ wh, int hs, int s,
    int z, int y, int x, const float* __restrict__ wA) {
  float acc = 0.f;
#pragma unroll
  for (int a = 0; a < 3; ++a) { int zz = z + a - 1; if ((unsigned)zz >= (unsigned)s) continue;
#pragma unroll
    for (int b = 0; b < 3; ++b) { int yy = y + b - 1; if ((unsigned)yy >= (unsigned)s) continue;
#pragma unroll
      for (int c = 0; c < 3; ++c) { int xx = x + c - 1; if ((unsigned)xx >= (unsigned)s) continue;
        acc = fmaf(wA[(a*3+b)*3+c], wh[((zz>>1)*hs + (yy>>1))*hs + (xx>>1)], acc);
      } } }
  return acc;
}

__global__ void __launch_bounds__(512) k_mg_small(
    float* __restrict__ w16, float* __restrict__ r_o,
    const float* __restrict__ rc2,
    const float* __restrict__ wA, const float* __restrict__ wr) {
  __shared__ float r16[4096];
  __shared__ float r8[512];
  __shared__ float r4[64];
  __shared__ float r2[8];
  __shared__ float wa[512];
  __shared__ float wb[64];
  __shared__ float scal[2];
  int tid = threadIdx.x;
  float diag = wA[13];
  float wrl[8];
#pragma unroll
  for (int j = 0; j < 8; ++j) wrl[j] = wr[j];

  for (int j = tid; j < 4096; j += 512) {
    int x = j & 15, y = (j >> 4) & 15, z = j >> 8;
    float s = 0.f;
#pragma unroll
    for (int a = 0; a < 2; ++a)
#pragma unroll
      for (int b = 0; b < 2; ++b)
#pragma unroll
        for (int c = 0; c < 2; ++c)
          s = fmaf(wrl[(a*2+b)*2+c], rc2[((2*z+a)*32 + (2*y+b))*32 + (2*x+c)], s);
    r16[j] = s;
  }
  __syncthreads();
  {
    int j = tid;
    int x = j & 7, y = (j >> 3) & 7, z = j >> 6;
    float s = 0.f;
#pragma unroll
    for (int a = 0; a < 2; ++a)
#pragma unroll
      for (int b = 0; b < 2; ++b)
#pragma unroll
        for (int c = 0; c < 2; ++c)
          s = fmaf(wrl[(a*2+b)*2+c], r16[((2*z+a)*16 + (2*y+b))*16 + (2*x+c)], s);
    r8[j] = s;
  }
  __syncthreads();
  if (tid < 64) {
    int x = tid & 3, y = (tid >> 2) & 3, z = tid >> 4;
    float s = 0.f;
#pragma unroll
    for (int a = 0; a < 2; ++a)
#pragma unroll
      for (int b = 0; b < 2; ++b)
#pragma unroll
        for (int c = 0; c < 2; ++c)
          s = fmaf(wrl[(a*2+b)*2+c], r8[((2*z+a)*8 + (2*y+b))*8 + (2*x+c)], s);
    r4[tid] = s;
  }
  __syncthreads();
  if (tid < 8) {
    int x = tid & 1, y = (tid >> 1) & 1, z = tid >> 2;
    float s = 0.f;
#pragma unroll
    for (int a = 0; a < 2; ++a)
#pragma unroll
      for (int b = 0; b < 2; ++b)
#pragma unroll
        for (int c = 0; c < 2; ++c)
          s = fmaf(wrl[(a*2+b)*2+c], r4[((2*z+a)*4 + (2*y+b))*4 + (2*x+c)], s);
    r2[tid] = s;
  }
  __syncthreads();
  if (tid == 0) {
    float s = 0.f;
#pragma unroll
    for (int j = 0; j < 8; ++j) s = fmaf(wrl[j], r2[j], s);
    scal[0] = s;
    r_o[0] = s;
    scal[1] = s / diag;
  }
  __syncthreads();
  if (tid < 8) {
    int x = tid & 1, y = (tid >> 1) & 1, z = tid >> 2;
    float wp = scal[1];
    float az = azb_prol(&scal[1], 1, 2, z, y, x, wA);
    wa[tid] = wp - az/diag + r2[tid]/diag;
  }
  __syncthreads();
  if (tid < 64) {
    int x = tid & 3, y = (tid >> 2) & 3, z = tid >> 4;
    float wp = wa[((z>>1)*2 + (y>>1))*2 + (x>>1)];
    float az = azb_prol(wa, 2, 4, z, y, x, wA);
    wb[tid] = wp - az/diag + r4[tid]/diag;
  }
  __syncthreads();
  {
    int j = tid;
    int x = j & 7, y = (j >> 3) & 7, z = j >> 6;
    float wp = wb[((z>>1)*4 + (y>>1))*4 + (x>>1)];
    float az = azb_prol(wb, 4, 8, z, y, x, wA);
    wa[j] = wp - az/diag + r8[j]/diag;
  }
  __syncthreads();
  for (int j = tid; j < 4096; j += 512) {
    int x = j & 15, y = (j >> 4) & 15, z = j >> 8;
    float wp = wa[((z>>1)*8 + (y>>1))*8 + (x>>1)];
    float az = azb_prol(wa, 8, 16, z, y, x, wA);
    w16[j] = wp - az/diag + r16[j]/diag;
  }
}

__global__ void __launch_bounds__(256) k_coarse_step(
    float* __restrict__ wout, const float* __restrict__ wh,
    const float* __restrict__ rl, const float* __restrict__ wA, int s) {
  int i = blockIdx.x*256 + threadIdx.x;
  int n3 = s*s*s;
  if (i >= n3) return;
  int x = i % s; int t = i / s; int y = t % s; int z = t / s;
  int hs = s >> 1;
  float diag = wA[13];
  float wp = wh[((z>>1)*hs + (y>>1))*hs + (x>>1)];
  float az = azb_prol(wh, hs, s, z, y, x, wA);
  wout[i] = wp - az/diag + rl[i]/diag;
}

__global__ void __launch_bounds__(256) k_pupd4(
    float* __restrict__ pdst, float* __restrict__ wmgo,
    const float* __restrict__ psrc, const float* __restrict__ rfine,
    const float* __restrict__ w64, const float* __restrict__ wA, int writeWmg) {
  int i4 = blockIdx.x*256 + threadIdx.x;
  if (i4 >= NF/4) return;
  int i = i4*4;
  int x = i & (NN-1); int t = i >> 7; int y = t & (NN-1); int z = t >> 7;
  float rdiag = 1.0f / wA[13];
  float2 w2 = *(const float2*)(w64 + ((size_t)(z>>1)*64 + (y>>1))*64 + (x>>1));
  float4 ps = ((const float4*)psrc)[i4];
  float4 rf = ((const float4*)rfine)[i4];
  float4 o = make_float4(ps.x - w2.x - rf.x*rdiag,
                         ps.y - w2.x - rf.y*rdiag,
                         ps.z - w2.y - rf.z*rdiag,
                         ps.w - w2.y - rf.w*rdiag);
  ((float4*)pdst)[i4] = o;
  if (writeWmg) ((float4*)wmgo)[i4] = make_float4(w2.x, w2.x, w2.y, w2.y);
}

__global__ void __launch_bounds__(256) k_proj3(
    float* __restrict__ u, float* __restrict__ v, float* __restrict__ w,
    const float* __restrict__ pf, const float* __restrict__ sg,
    const float* __restrict__ wx, const float* __restrict__ wy,
    const float* __restrict__ wz, const float* __restrict__ dtp) {
  int x0 = threadIdx.x * 4;
  int y  = blockIdx.x * 8 + threadIdx.y;
  int z  = blockIdx.y;
  bool lo = (x0 == 0), hi = (x0 == NN-4);
  int rb[9]; bool rn[9];
  prep9(z, y, rb, rn);
  float aP[3][4] = {};
  sten_p3(pf, rb, lo, hi, x0, wx, wy, wz, aP);
  float dt = dtp[0];
  int i4 = ((z*NN + y)*NN + x0) >> 2;
  float4 u4 = ((const float4*)u)[i4];
  float4 v4 = ((const float4*)v)[i4];
  float4 w4 = ((const float4*)w)[i4];
  float4 sg4 = ((const float4*)sg)[i4];
  float ua[4] = {u4.x, u4.y, u4.z, u4.w};
  float va[4] = {v4.x, v4.y, v4.z, v4.w};
  float wa[4] = {w4.x, w4.y, w4.z, w4.w};
  float sa[4] = {sg4.x, sg4.y, sg4.z, sg4.w};
  float ou[4], ov[4], ow[4];
#pragma unroll
  for (int k = 0; k < 4; ++k) {
    float rd = 1.0f / (1.0f + dt*sa[k]);
    ou[k] = (ua[k] - aP[0][k]*dt)*rd;
    ov[k] = (va[k] - aP[1][k]*dt)*rd;
    ow[k] = (wa[k] - aP[2][k]*dt)*rd;
  }
  ((float4*)u)[i4] = make_float4(ou[0], ou[1], ou[2], ou[3]);
  ((float4*)v)[i4] = make_float4(ov[0], ov[1], ov[2], ov[3]);
  ((float4*)w)[i4] = make_float4(ow[0], ow[1], ow[2], ow[3]);
}

// ---------- launch ----------

extern "C" void kernel_launch(void* const* d_in, const int* in_sizes, int n_in,
                              void* d_out, int out_size, void* d_ws, size_t ws_size,
                              hipStream_t stream) {
  const float* values_u = (const float*)d_in[0];
  const float* values_v = (const float*)d_in[1];
  const float* values_w = (const float*)d_in[2];
  const float* values_p = (const float*)d_in[3];
  const float* sigma    = (const float*)d_in[4];
  const float* wx       = (const float*)d_in[5];
  const float* wy       = (const float*)d_in[6];
  const float* wz       = (const float*)d_in[7];
  const float* wd       = (const float*)d_in[8];
  const float* wA       = (const float*)d_in[9];
  const float* wr       = (const float*)d_in[10];
  const float* dtp      = (const float*)d_in[11];

  float* out   = (float*)d_out;
  float* u_o   = out;
  float* v_o   = out + (size_t)NF;
  float* w_o   = out + (size_t)2*NF;
  float* p_o   = out + (size_t)3*NF;
  float* wmg_o = out + (size_t)4*NF;
  float* r_o   = out + (size_t)5*NF;

  float* ws    = (float*)d_ws;
  float* f0    = ws;
  float* f1    = f0 + (size_t)NF;
  float* f2    = f1 + (size_t)NF;
  float* bws   = f2 + (size_t)NF;
  float* rfine = bws + (size_t)NF;
  float* pbuf  = rfine + (size_t)NF;
  float* gqu   = pbuf + (size_t)NF;
  float* gqv   = gqu + (size_t)NF;
  float* gqw   = gqv + (size_t)NF;
  float* ap0   = gqw + (size_t)NF;
  float* rc1   = ap0 + (size_t)NF;       // 64^3
  float* rc2   = rc1 + 262144;           // 32^3
  float* w16   = rc2 + 32768;            // 16^3
  float* w32   = w16 + 4096;             // 32^3
  float* w64   = w32 + 32768;            // 64^3

  const int TB = 256;
  dim3 blkS(32, 8, 1);
  dim3 grdS(16, 128, 1);   // plane-major for L1-path stencil kernels
  dim3 blkG(32, 8, 1);
  dim3 grdG(16, 32, 1);    // gld march: 16 ybands x 32 zsegs (ZSEG=4)

  k_prep<<<grdS, blkS, 0, stream>>>(u_o, v_o, w_o, gqu, gqv, gqw, ap0,
                                    values_u, values_v, values_w, values_p, sigma,
                                    wx, wy, wz, wA, dtp);
  k_mom3_gld<<<grdG, blkG, 0, stream>>>(f0, f1, f2, u_o, v_o, w_o, gqu, gqv, gqw,
                                        sigma, wx, wy, wz, wd, dtp, 0.5f);
  k_mom3_gld<<<grdG, blkG, 0, stream>>>(u_o, v_o, w_o, f0, f1, f2, gqu, gqv, gqw,
                                        sigma, wx, wy, wz, wd, dtp, 1.0f);

  // it 0
  k_bdiv_gld<<<grdG, blkG, 0, stream>>>(bws, rfine, u_o, v_o, w_o, ap0,
                                        wx, wy, wz, dtp);
  k_restrict<<<1024, TB, 0, stream>>>(rc1, rfine, wr, 64);
  k_restrict<<<128, TB, 0, stream>>>(rc2, rc1, wr, 32);
  k_mg_small<<<1, 512, 0, stream>>>(w16, r_o, rc2, wA, wr);
  k_coarse_step<<<128, TB, 0, stream>>>(w32, w16, rc2, wA, 32);
  k_coarse_step<<<1024, TB, 0, stream>>>(w64, w32, rc1, wA, 64);
  k_pupd4<<<NF/4/TB, TB, 0, stream>>>(pbuf, wmg_o, values_p, rfine, w64, wA, 0);

  // it 1
  k_resres1<<<1024, TB, 0, stream>>>(rfine, rc1, pbuf, bws, wA, wr);
  k_restrict<<<128, TB, 0, stream>>>(rc2, rc1, wr, 32);
  k_mg_small<<<1, 512, 0, stream>>>(w16, r_o, rc2, wA, wr);
  k_coarse_step<<<128, TB, 0, stream>>>(w32, w16, rc2, wA, 32);
  k_coarse_step<<<1024, TB, 0, stream>>>(w64, w32, rc1, wA, 64);
  k_pupd4<<<NF/4/TB, TB, 0, stream>>>(p_o, wmg_o, pbuf, rfine, w64, wA, 1);

  k_proj3<<<grdS, blkS, 0, stream>>>(u_o, v_o, w_o, p_o, sigma, wx, wy, wz, dtp);
}